// Round 14
// baseline (243.933 us; speedup 1.0000x reference)
//
#include <hip/hip_runtime.h>
#include <hip/hip_bf16.h>
#include <stdint.h>

// 2-layer GCN, N=100000, E=3200000, F=128, H=64.
// out = b2 + (1/N)*( sum_i dinv[i]*yp[i] + sum_e yp[row_e]*dinv[col_e] )
//     = b2 + (1/N)* sum_i (srcsum[i] + dinv[i]) * yp[i],
//       srcsum[j] = sum_{e: row=j} dinv[col_e]     <-- no gathers needed!
// yp[i] = dinv[i]*relu(b1 + dinv[i]*(sum_{e:col=i} xws[row] + xws[i])).W2
// xws[j] = dinv[j]*(x@W1)[j] stored FP8 e4m3, 64B rows.
// HW model (measured r1-r13):
//  - random gathers cost ~1 L1 line-fill per ~13cyc per CU, independent of
//    row bytes or L2 residency -> 3.2M fills ~= 66us floor. k_agg pays it
//    once (unavoidable); the old final2 paid it AGAIN for yp -> eliminated
//    by regrouping the edge term by source. dinv[col] is attached while
//    col-grouped (zval, coalesced), then row-keyed counting sort (all
//    coalesced), then per-bucket LDS accumulate + fused dot.
//  - global atomics are memory-side ~32B RMW: zero on edge path.
//  - SAME-ADDRESS global atomics serialize ~12ns: per-block partials.
//  - scattered 4B global writes: LDS-group tiles, write coalesced runs.

#define F_IN 128
#define H_DIM 64
#define BKT_SH 8
#define BKT_SZ 256
#define MAXBKT 512
#define PWG 256
#define PTHR 256
#define PPTHR 512
#define TILE 4096
#define CSR_CAP 10240
#define PARTMAX 2048

typedef int   i4 __attribute__((ext_vector_type(4)));
typedef float f4 __attribute__((ext_vector_type(4)));
typedef float fv2 __attribute__((ext_vector_type(2)));

#if defined(__has_builtin)
#if __has_builtin(__builtin_amdgcn_cvt_pk_f32_fp8) && __has_builtin(__builtin_amdgcn_cvt_pk_fp8_f32)
#define HW_FP8 1
#endif
#endif

__device__ __forceinline__ float sw_dec_e4m3(unsigned b) {
    unsigned s = b & 0x80, e = (b >> 3) & 15, mm = b & 7;
    float v;
    if (e) v = __uint_as_float(((e + 120u) << 23) | (mm << 20));
    else   v = (float)mm * 0.001953125f;
    return s ? -v : v;
}
__device__ __forceinline__ unsigned sw_enc_e4m3(float f) {
    unsigned s = (__float_as_uint(f) & 0x80000000u) ? 0x80u : 0u;
    float a = fminf(fabsf(f), 448.0f);
    if (a < 9.765625e-4f) return s;
    if (a < 0.015625f) {
        int k = (int)rintf(a * 512.0f);
        if (k > 7) return s | 0x08;
        return s | (unsigned)k;
    }
    int e; float mant = frexpf(a, &e);
    int q = (int)rintf((mant * 2.0f - 1.0f) * 8.0f);
    int E = e - 1;
    if (q == 8) { q = 0; E += 1; }
    if (E > 8) { E = 8; q = 6; }
    return s | ((unsigned)(E + 7) << 3) | (unsigned)q;
}

__device__ __forceinline__ float2 f8pair(unsigned u) {   // 2 fp8 in low 16 bits
#ifdef HW_FP8
    fv2 r = __builtin_amdgcn_cvt_pk_f32_fp8((int)u, false);
    return make_float2(r.x, r.y);
#else
    return make_float2(sw_dec_e4m3(u & 0xff), sw_dec_e4m3((u >> 8) & 0xff));
#endif
}
__device__ __forceinline__ unsigned f8pack4(float v0, float v1, float v2, float v3) {
#ifdef HW_FP8
    unsigned pk = (unsigned)__builtin_amdgcn_cvt_pk_fp8_f32(v0, v1, 0, false);
    pk = (unsigned)__builtin_amdgcn_cvt_pk_fp8_f32(v2, v3, (int)pk, true);
    return pk;
#else
    return sw_enc_e4m3(v0) | (sw_enc_e4m3(v1) << 8) |
           (sw_enc_e4m3(v2) << 16) | (sw_enc_e4m3(v3) << 24);
#endif
}

__device__ __forceinline__ ushort f2bf(float v) {        // f32 -> bf16 (rne)
    unsigned u = __float_as_uint(v);
    return (ushort)((u + 0x7fffu + ((u >> 16) & 1u)) >> 16);
}
__device__ __forceinline__ float bf2f(ushort b) {
    return __uint_as_float(((unsigned)b) << 16);
}

// ---------- pass 1: per-WG bucket histogram over col (LDS) ----------
__global__ __launch_bounds__(PTHR) void k_hist1(const int* __restrict__ col,
                                                int* __restrict__ histG,
                                                int E, int nbkt, int chunk) {
    __shared__ int h[MAXBKT];
    for (int i = threadIdx.x; i < nbkt; i += PTHR) h[i] = 0;
    __syncthreads();
    int s = blockIdx.x * chunk, e = min(E, s + chunk);
    if (s < e) {
        int s4 = s >> 2, e4 = e >> 2;
        const i4* c4 = (const i4*)col;
        int t = s4 + threadIdx.x;
        for (; t + 3 * PTHR < e4; t += 4 * PTHR) {
            i4 a = __builtin_nontemporal_load(c4 + t);
            i4 b = __builtin_nontemporal_load(c4 + t + PTHR);
            i4 c = __builtin_nontemporal_load(c4 + t + 2 * PTHR);
            i4 d = __builtin_nontemporal_load(c4 + t + 3 * PTHR);
            atomicAdd(&h[(unsigned)a.x >> BKT_SH], 1); atomicAdd(&h[(unsigned)a.y >> BKT_SH], 1);
            atomicAdd(&h[(unsigned)a.z >> BKT_SH], 1); atomicAdd(&h[(unsigned)a.w >> BKT_SH], 1);
            atomicAdd(&h[(unsigned)b.x >> BKT_SH], 1); atomicAdd(&h[(unsigned)b.y >> BKT_SH], 1);
            atomicAdd(&h[(unsigned)b.z >> BKT_SH], 1); atomicAdd(&h[(unsigned)b.w >> BKT_SH], 1);
            atomicAdd(&h[(unsigned)c.x >> BKT_SH], 1); atomicAdd(&h[(unsigned)c.y >> BKT_SH], 1);
            atomicAdd(&h[(unsigned)c.z >> BKT_SH], 1); atomicAdd(&h[(unsigned)c.w >> BKT_SH], 1);
            atomicAdd(&h[(unsigned)d.x >> BKT_SH], 1); atomicAdd(&h[(unsigned)d.y >> BKT_SH], 1);
            atomicAdd(&h[(unsigned)d.z >> BKT_SH], 1); atomicAdd(&h[(unsigned)d.w >> BKT_SH], 1);
        }
        for (; t < e4; t += PTHR) {
            i4 a = __builtin_nontemporal_load(c4 + t);
            atomicAdd(&h[(unsigned)a.x >> BKT_SH], 1); atomicAdd(&h[(unsigned)a.y >> BKT_SH], 1);
            atomicAdd(&h[(unsigned)a.z >> BKT_SH], 1); atomicAdd(&h[(unsigned)a.w >> BKT_SH], 1);
        }
        for (int i = (e4 << 2) + threadIdx.x; i < e; i += PTHR)
            atomicAdd(&h[(unsigned)col[i] >> BKT_SH], 1);
    }
    __syncthreads();
    for (int i = threadIdx.x; i < nbkt; i += PTHR)
        histG[(size_t)i * PWG + blockIdx.x] = h[i];
}

// ---------- histogram over part's rowid (key = part>>16) ----------
__global__ __launch_bounds__(PTHR) void k_hist2(const unsigned int* __restrict__ part,
                                                int* __restrict__ histG,
                                                int E, int nbkt, int chunk) {
    __shared__ int h[MAXBKT];
    for (int i = threadIdx.x; i < nbkt; i += PTHR) h[i] = 0;
    __syncthreads();
    int s = blockIdx.x * chunk, e = min(E, s + chunk);
    if (s < e) {
        int s4 = s >> 2, e4 = e >> 2;
        const i4* c4 = (const i4*)part;
        int t = s4 + threadIdx.x;
        for (; t < e4; t += PTHR) {
            i4 a = __builtin_nontemporal_load(c4 + t);
            atomicAdd(&h[(unsigned)a.x >> 16], 1); atomicAdd(&h[(unsigned)a.y >> 16], 1);
            atomicAdd(&h[(unsigned)a.z >> 16], 1); atomicAdd(&h[(unsigned)a.w >> 16], 1);
        }
        for (int i = (e4 << 2) + threadIdx.x; i < e; i += PTHR)
            atomicAdd(&h[part[i] >> 16], 1);
    }
    __syncthreads();
    for (int i = threadIdx.x; i < nbkt; i += PTHR)
        histG[(size_t)i * PWG + blockIdx.x] = h[i];
}

// ---------- per-bucket exclusive scan over WGs (in place) ----------
__global__ __launch_bounds__(PWG) void k_hscan_a(int* __restrict__ histG,
                                                 int* __restrict__ total, int nbkt) {
    __shared__ int s[PWG];
    int b = blockIdx.x, t = threadIdx.x;
    int v = histG[(size_t)b * PWG + t];
    s[t] = v;
    __syncthreads();
    for (int d = 1; d < PWG; d <<= 1) {
        int a = (t >= d) ? s[t - d] : 0;
        __syncthreads();
        s[t] += a;
        __syncthreads();
    }
    histG[(size_t)b * PWG + t] = s[t] - v;
    if (t == PWG - 1) total[b] = s[t];
}

// ---------- bucket starts ----------
__global__ __launch_bounds__(1024) void k_hscan_b(const int* __restrict__ total,
                                                  int* __restrict__ bstart, int nbkt) {
    __shared__ int s[1024];
    int t = threadIdx.x;
    int v = (t < nbkt) ? total[t] : 0;
    s[t] = v;
    __syncthreads();
    for (int d = 1; d < 1024; d <<= 1) {
        int a = (t >= d) ? s[t - d] : 0;
        __syncthreads();
        s[t] += a;
        __syncthreads();
    }
    if (t < nbkt) bstart[t] = s[t] - v;
    if (t == nbkt - 1) bstart[nbkt] = s[t];
}

// ---------- col-keyed tile multisplit -> part[] coalesced runs ----------
__global__ __launch_bounds__(PPTHR) void k_part(const int* __restrict__ row,
                                                const int* __restrict__ col,
                                                const int* __restrict__ histG,
                                                const int* __restrict__ bstart,
                                                unsigned int* __restrict__ part,
                                                int E, int nbkt, int chunk) {
    __shared__ int hist[MAXBKT], hbase[MAXBKT], curl[MAXBKT], gcur[MAXBKT];
    __shared__ int ssc[PPTHR];
    __shared__ unsigned grouped[TILE];
    __shared__ ushort bkt16[TILE];
    int tid = threadIdx.x, wg = blockIdx.x;
    for (int i = tid; i < nbkt; i += PPTHR)
        gcur[i] = bstart[i] + histG[(size_t)i * PWG + wg];
    int s = wg * chunk, e = min(E, s + chunk);
    for (int ts = s; ts < e; ts += TILE) {
        int te = min(e, ts + TILE), tc = te - ts;
        for (int i = tid; i < nbkt; i += PPTHR) hist[i] = 0;
        __syncthreads();
        for (int i = ts + tid; i < te; i += PPTHR)
            atomicAdd(&hist[(unsigned)col[i] >> BKT_SH], 1);
        __syncthreads();
        int v = (tid < nbkt) ? hist[tid] : 0;
        ssc[tid] = v;
        __syncthreads();
        for (int d = 1; d < PPTHR; d <<= 1) {
            int a = (tid >= d) ? ssc[tid - d] : 0;
            __syncthreads();
            ssc[tid] += a;
            __syncthreads();
        }
        if (tid < nbkt) { hbase[tid] = ssc[tid] - v; curl[tid] = ssc[tid] - v; }
        __syncthreads();
        for (int i = ts + tid; i < te; i += PPTHR) {
            int c = col[i], r = row[i];
            int b = (unsigned)c >> BKT_SH;
            int p = atomicAdd(&curl[b], 1);
            grouped[p] = ((unsigned)r << BKT_SH) | (unsigned)(c & (BKT_SZ - 1));
            bkt16[p] = (ushort)b;
        }
        __syncthreads();
        for (int q = tid; q < tc; q += PPTHR) {
            int b = bkt16[q];
            part[gcur[b] + (q - hbase[b])] = grouped[q];
        }
        __syncthreads();
        for (int i = tid; i < nbkt; i += PPTHR) gcur[i] += hist[i];
        __syncthreads();
    }
}

// ---------- row-keyed tile multisplit over (part, zval) -> epk[] ----------
// key = part>>16 (rowid>>8); payload = (rowLocal<<16) | bf16(dinv[col])
__global__ __launch_bounds__(PPTHR) void k_part2(const unsigned int* __restrict__ part,
                                                 const float* __restrict__ zval,
                                                 const int* __restrict__ histG,
                                                 const int* __restrict__ bstart,
                                                 unsigned int* __restrict__ epk,
                                                 int E, int nbkt, int chunk) {
    __shared__ int hist[MAXBKT], hbase[MAXBKT], curl[MAXBKT], gcur[MAXBKT];
    __shared__ int ssc[PPTHR];
    __shared__ unsigned grouped[TILE];
    __shared__ ushort bkt16[TILE];
    int tid = threadIdx.x, wg = blockIdx.x;
    for (int i = tid; i < nbkt; i += PPTHR)
        gcur[i] = bstart[i] + histG[(size_t)i * PWG + wg];
    int s = wg * chunk, e = min(E, s + chunk);
    for (int ts = s; ts < e; ts += TILE) {
        int te = min(e, ts + TILE), tc = te - ts;
        for (int i = tid; i < nbkt; i += PPTHR) hist[i] = 0;
        __syncthreads();
        for (int i = ts + tid; i < te; i += PPTHR)
            atomicAdd(&hist[part[i] >> 16], 1);
        __syncthreads();
        int v = (tid < nbkt) ? hist[tid] : 0;
        ssc[tid] = v;
        __syncthreads();
        for (int d = 1; d < PPTHR; d <<= 1) {
            int a = (tid >= d) ? ssc[tid - d] : 0;
            __syncthreads();
            ssc[tid] += a;
            __syncthreads();
        }
        if (tid < nbkt) { hbase[tid] = ssc[tid] - v; curl[tid] = ssc[tid] - v; }
        __syncthreads();
        for (int i = ts + tid; i < te; i += PPTHR) {
            unsigned u = part[i];
            int b = u >> 16;
            unsigned rl = (u >> BKT_SH) & (BKT_SZ - 1);
            int p = atomicAdd(&curl[b], 1);
            grouped[p] = (rl << 16) | (unsigned)f2bf(zval[i]);
            bkt16[p] = (ushort)b;
        }
        __syncthreads();
        for (int q = tid; q < tc; q += PPTHR) {
            int b = bkt16[q];
            epk[gcur[b] + (q - hbase[b])] = grouped[q];
        }
        __syncthreads();
        for (int i = tid; i < nbkt; i += PPTHR) gcur[i] += hist[i];
        __syncthreads();
    }
}

// ---------- per-bucket: degrees, offs, dinv, zval; csr staged in LDS ----------
__global__ __launch_bounds__(PTHR) void k_csr(const unsigned int* __restrict__ part,
                                              const int* __restrict__ bstart,
                                              int* __restrict__ offs,
                                              float* __restrict__ dinv,
                                              int* __restrict__ csr,
                                              float* __restrict__ zval,
                                              int N, int E, int nbkt) {
    __shared__ int dg[BKT_SZ], sc[BKT_SZ], cur[BKT_SZ];
    __shared__ float sdinv[BKT_SZ];
    __shared__ int stage[CSR_CAP];
    int b = blockIdx.x, tid = threadIdx.x;   // PTHR == BKT_SZ
    dg[tid] = 0;
    __syncthreads();
    int s = bstart[b], e = bstart[b + 1], cnt = e - s;
    for (int i = s + tid; i < e; i += PTHR)
        atomicAdd(&dg[part[i] & (BKT_SZ - 1)], 1);
    __syncthreads();
    int v = dg[tid];
    sc[tid] = v;
    __syncthreads();
    for (int d = 1; d < BKT_SZ; d <<= 1) {
        int a = (tid >= d) ? sc[tid - d] : 0;
        __syncthreads();
        sc[tid] += a;
        __syncthreads();
    }
    int ex = sc[tid] - v;
    cur[tid] = ex;
    float dv = rsqrtf((float)v + 1.0f);      // +1 self loop
    sdinv[tid] = dv;
    int g = b * BKT_SZ + tid;
    if (g < N) {
        offs[g] = s + ex;
        dinv[g] = dv;
    }
    if (b == 0 && tid == 0) offs[N] = E;
    __syncthreads();
    if (cnt <= CSR_CAP) {
        for (int i = s + tid; i < e; i += PTHR) {
            unsigned u = part[i];
            int cl = u & (BKT_SZ - 1);
            zval[i] = sdinv[cl];             // coalesced, aligned with part
            int p = atomicAdd(&cur[cl], 1);
            stage[p] = (int)(u >> BKT_SH);
        }
        __syncthreads();
        for (int q = tid; q < cnt; q += PTHR)
            csr[s + q] = stage[q];           // coalesced
    } else {
        for (int i = s + tid; i < e; i += PTHR) {
            unsigned u = part[i];
            int cl = u & (BKT_SZ - 1);
            zval[i] = sdinv[cl];
            int p = atomicAdd(&cur[cl], 1);
            csr[s + p] = (int)(u >> BKT_SH);
        }
    }
}

// ---------- xws = dinv * (x @ W1), fp8 e4m3 (64B rows) ----------
__global__ __launch_bounds__(256) void k_gemm1(const float* __restrict__ x,
                                               const float* __restrict__ W1,
                                               const float* __restrict__ dinv,
                                               unsigned int* __restrict__ xw8,
                                               int N) {
    __shared__ float xs[64 * 132];
    __shared__ float ws[128 * 64];
    int tid = threadIdx.x;
    int row0 = blockIdx.x * 64;

    const float4* w4 = (const float4*)W1;
    float4* ws4 = (float4*)ws;
#pragma unroll
    for (int i = 0; i < 8; i++) ws4[tid + 256 * i] = w4[tid + 256 * i];

#pragma unroll
    for (int i = 0; i < 8; i++) {
        int idx = tid + 256 * i;
        int r = idx >> 5;
        int c = idx & 31;
        f4 v = {0.f, 0.f, 0.f, 0.f};
        int gr = row0 + r;
        if (gr < N) v = __builtin_nontemporal_load((const f4*)x + (size_t)gr * 32 + c);
        *(f4*)&xs[r * 132 + c * 4] = v;
    }
    __syncthreads();

    int tx = tid & 15, ty = tid >> 4;
    float acc[4][4] = {};
#pragma unroll 4
    for (int k = 0; k < 128; k++) {
        float4 wv = *(const float4*)&ws[k * 64 + tx * 4];
#pragma unroll
        for (int i = 0; i < 4; i++) {
            float xv = xs[(ty * 4 + i) * 132 + k];
            acc[i][0] += xv * wv.x;
            acc[i][1] += xv * wv.y;
            acc[i][2] += xv * wv.z;
            acc[i][3] += xv * wv.w;
        }
    }
#pragma unroll
    for (int i = 0; i < 4; i++) {
        int gr = row0 + ty * 4 + i;
        if (gr < N) {
            float dsc = dinv[gr];
            unsigned pk = f8pack4(acc[i][0] * dsc, acc[i][1] * dsc,
                                  acc[i][2] * dsc, acc[i][3] * dsc);
            xw8[(size_t)gr * 16 + tx] = pk;   // row = 16 u32 = 64 fp8
        }
    }
}

// ---------- aggregation: one wave per node, half-wave ushort fp8 gathers ----------
__global__ __launch_bounds__(256) void k_agg(const ushort* __restrict__ xw8,
                                             const int* __restrict__ csr,
                                             const int* __restrict__ offs,
                                             const float* __restrict__ dinv,
                                             const float* __restrict__ b1,
                                             const float* __restrict__ W2,
                                             float* __restrict__ yp, int N) {
    int wid = (blockIdx.x * blockDim.x + threadIdx.x) >> 6;
    int lane = threadIdx.x & 63;
    if (wid >= N) return;
    int m = lane & 31, half = lane >> 5;

    float di = dinv[wid];
    float2 bv = ((const float2*)b1)[m];
    float2 wv = ((const float2*)W2)[m];

    float a0 = 0.f, a1 = 0.f;
    if (half == 0) {          // self loop counted once
        float2 sv = f8pair(xw8[(size_t)wid * 32 + m]);
        a0 += sv.x; a1 += sv.y;
    }
    int p = offs[wid], pe = offs[wid + 1];
    for (; p + 16 <= pe; p += 16) {
        int j0 = csr[p + 0 + half];
        int j1 = csr[p + 2 + half];
        int j2 = csr[p + 4 + half];
        int j3 = csr[p + 6 + half];
        int j4 = csr[p + 8 + half];
        int j5 = csr[p + 10 + half];
        int j6 = csr[p + 12 + half];
        int j7 = csr[p + 14 + half];
        ushort u0 = xw8[(size_t)j0 * 32 + m];
        ushort u1 = xw8[(size_t)j1 * 32 + m];
        ushort u2 = xw8[(size_t)j2 * 32 + m];
        ushort u3 = xw8[(size_t)j3 * 32 + m];
        ushort u4 = xw8[(size_t)j4 * 32 + m];
        ushort u5 = xw8[(size_t)j5 * 32 + m];
        ushort u6 = xw8[(size_t)j6 * 32 + m];
        ushort u7 = xw8[(size_t)j7 * 32 + m];
        float2 v0 = f8pair(u0), v1 = f8pair(u1), v2 = f8pair(u2), v3 = f8pair(u3);
        float2 v4 = f8pair(u4), v5 = f8pair(u5), v6 = f8pair(u6), v7 = f8pair(u7);
        a0 += ((v0.x + v1.x) + (v2.x + v3.x)) + ((v4.x + v5.x) + (v6.x + v7.x));
        a1 += ((v0.y + v1.y) + (v2.y + v3.y)) + ((v4.y + v5.y) + (v6.y + v7.y));
    }
    for (; p + 8 <= pe; p += 8) {
        int j0 = csr[p + 0 + half];
        int j1 = csr[p + 2 + half];
        int j2 = csr[p + 4 + half];
        int j3 = csr[p + 6 + half];
        float2 v0 = f8pair(xw8[(size_t)j0 * 32 + m]);
        float2 v1 = f8pair(xw8[(size_t)j1 * 32 + m]);
        float2 v2 = f8pair(xw8[(size_t)j2 * 32 + m]);
        float2 v3 = f8pair(xw8[(size_t)j3 * 32 + m]);
        a0 += (v0.x + v1.x) + (v2.x + v3.x);
        a1 += (v0.y + v1.y) + (v2.y + v3.y);
    }
    for (; p + 2 <= pe; p += 2) {
        int j = csr[p + half];
        float2 v = f8pair(xw8[(size_t)j * 32 + m]);
        a0 += v.x; a1 += v.y;
    }
    if (p < pe && half == 0) {     // odd tail edge
        int j = csr[p];
        float2 v = f8pair(xw8[(size_t)j * 32 + m]);
        a0 += v.x; a1 += v.y;
    }
    a0 += __shfl_xor(a0, 32, 64);
    a1 += __shfl_xor(a1, 32, 64);
    float h0 = fmaxf(bv.x + di * a0, 0.f);
    float h1 = fmaxf(bv.y + di * a1, 0.f);
    float v = h0 * wv.x + h1 * wv.y;
#pragma unroll
    for (int d = 16; d > 0; d >>= 1) v += __shfl_xor(v, d, 64);
    if (lane == 0) yp[wid] = di * v;
}

// ---------- per-row-bucket: accumulate srcsum in LDS, fused dot + node term ----------
__global__ __launch_bounds__(PTHR) void k_srcsum(const unsigned int* __restrict__ epk,
                                                 const int* __restrict__ bstart2,
                                                 const float* __restrict__ dinv,
                                                 const float* __restrict__ yp,
                                                 float* __restrict__ partial, int N) {
    __shared__ float acc[BKT_SZ];
    int b = blockIdx.x, tid = threadIdx.x;   // PTHR == BKT_SZ
    acc[tid] = 0.f;
    __syncthreads();
    int s = bstart2[b], e = bstart2[b + 1];
    for (int i = s + tid; i < e; i += PTHR) {
        unsigned u = epk[i];
        atomicAdd(&acc[u >> 16], bf2f((ushort)(u & 0xffffu)));
    }
    __syncthreads();
    int g = b * BKT_SZ + tid;
    float local = 0.f;
    if (g < N) local = (acc[tid] + dinv[g]) * yp[g];
#pragma unroll
    for (int d = 32; d > 0; d >>= 1) local += __shfl_xor(local, d, 64);
    __shared__ float wsum[4];
    int lane = tid & 63, w = tid >> 6;
    if (lane == 0) wsum[w] = local;
    __syncthreads();
    if (tid == 0) partial[b] = (wsum[0] + wsum[1]) + (wsum[2] + wsum[3]);
}

// ---------- reduce partials + write ----------
__global__ __launch_bounds__(256) void k_write(const float* __restrict__ partial,
                                               const float* __restrict__ b2,
                                               float* __restrict__ out, int nb, int N) {
    float s = 0.f;
    for (int i = threadIdx.x; i < nb; i += 256) s += partial[i];
#pragma unroll
    for (int d = 32; d > 0; d >>= 1) s += __shfl_xor(s, d, 64);
    __shared__ float wsum[4];
    int lane = threadIdx.x & 63, w = threadIdx.x >> 6;
    if (lane == 0) wsum[w] = s;
    __syncthreads();
    if (threadIdx.x == 0)
        out[0] = b2[0] + ((wsum[0] + wsum[1]) + (wsum[2] + wsum[3])) / (float)N;
}

extern "C" void kernel_launch(void* const* d_in, const int* in_sizes, int n_in,
                              void* d_out, int out_size, void* d_ws, size_t ws_size,
                              hipStream_t stream) {
    const float* x  = (const float*)d_in[0];
    const int*   ei = (const int*)d_in[1];
    const float* W1 = (const float*)d_in[2];
    const float* b1 = (const float*)d_in[3];
    const float* W2 = (const float*)d_in[4];
    const float* b2 = (const float*)d_in[5];

    int N = in_sizes[0] / F_IN;
    int E = in_sizes[1] / 2;
    const int* erow = ei;        // sources
    const int* ecol = ei + E;    // targets

    int NBKT = (N + BKT_SZ - 1) >> BKT_SH;          // 391
    int chunk = (((E + PWG - 1) / PWG) + 3) & ~3;   // 4-aligned chunks

    char* w = (char*)d_ws;
    auto take = [&](size_t bytes) {
        char* p = w;
        w += (bytes + 255) & ~(size_t)255;
        return p;
    };
    int*          histG   = (int*)take((size_t)NBKT * PWG * 4);
    int*          histG2  = (int*)take((size_t)NBKT * PWG * 4);
    int*          total   = (int*)take((size_t)NBKT * 4);
    int*          total2  = (int*)take((size_t)NBKT * 4);
    int*          bstart  = (int*)take((size_t)(NBKT + 1) * 4);
    int*          bstart2 = (int*)take((size_t)(NBKT + 1) * 4);
    unsigned int* part    = (unsigned int*)take((size_t)E * 4);
    unsigned int* epk     = (unsigned int*)take((size_t)E * 4);
    int*          csr     = (int*)take((size_t)E * 4);
    float*        zval    = (float*)take((size_t)E * 4);
    int*          offs    = (int*)take((size_t)(N + 1) * 4);
    float*        dinv    = (float*)take((size_t)N * 4);
    float*        yp      = (float*)take((size_t)N * 4);
    float*        partial = (float*)take((size_t)PARTMAX * 4);
    unsigned int* xw8     = (unsigned int*)take((size_t)N * H_DIM);
    (void)ws_size;

    float* out = (float*)d_out;

    k_hist1<<<PWG, PTHR, 0, stream>>>(ecol, histG, E, NBKT, chunk);
    k_hscan_a<<<NBKT, PWG, 0, stream>>>(histG, total, NBKT);
    k_hscan_b<<<1, 1024, 0, stream>>>(total, bstart, NBKT);
    k_part<<<PWG, PPTHR, 0, stream>>>(erow, ecol, histG, bstart, part, E, NBKT, chunk);
    k_csr<<<NBKT, PTHR, 0, stream>>>(part, bstart, offs, dinv, csr, zval, N, E, NBKT);
    k_hist2<<<PWG, PTHR, 0, stream>>>(part, histG2, E, NBKT, chunk);
    k_hscan_a<<<NBKT, PWG, 0, stream>>>(histG2, total2, NBKT);
    k_hscan_b<<<1, 1024, 0, stream>>>(total2, bstart2, NBKT);
    k_part2<<<PWG, PPTHR, 0, stream>>>(part, zval, histG2, bstart2, epk, E, NBKT, chunk);
    k_gemm1<<<(N + 63) / 64, 256, 0, stream>>>(x, W1, dinv, xw8, N);
    k_agg<<<((size_t)N * 64 + 255) / 256, 256, 0, stream>>>((const ushort*)xw8, csr, offs, dinv, b1, W2, yp, N);
    k_srcsum<<<NBKT, PTHR, 0, stream>>>(epk, bstart2, dinv, yp, partial, N);
    k_write<<<1, 256, 0, stream>>>(partial, b2, out, NBKT, N);
}

// Round 15
// 195.452 us; speedup vs baseline: 1.2480x; 1.2480x over previous
//
#include <hip/hip_runtime.h>
#include <hip/hip_bf16.h>
#include <stdint.h>

// 2-layer GCN, N=100000, E=3200000, F=128, H=64.
// out = b2 + (1/N)*sum_i dinv[i]*( yp[i] + sum_{j in Nin(i)} yp[j] )
// yp[i] = dinv[i]*relu(b1 + dinv[i]*(sum_{e:col=i} xws[row] + xws[i])).W2
// xws[j] = dinv[j]*(x@W1)[j] stored FP8 e4m3, 64B rows (single table).
// HW model (measured r1-r14):
//  - random gathers cost ~1 L1 line-fill per ~13cyc per CU, independent of
//    row bytes (32-128B) and L2 residency -> 3.2M fills ~= 66us floor.
//    k_agg pays it once; final2 pays it once more for yp. BOTH regrouping
//    alternatives (4-pass LDS predication r13, row-keyed 2nd sort r14)
//    cost MORE than the gather they replace -> this structure is final.
//    Only lever: L1 hit fraction -> final2 gathers bf16 yph (200KB table).
//  - global atomics are memory-side ~32B RMW each: zero on edge path.
//  - SAME-ADDRESS global atomics serialize ~12ns: per-block partials.
//  - scattered 4B global writes: LDS-group tiles, write coalesced runs
//    (k_part tile multisplit, k_csr LDS staging).

#define F_IN 128
#define H_DIM 64
#define BKT_SH 8
#define BKT_SZ 256
#define MAXBKT 512
#define PWG 256
#define PTHR 256
#define PPTHR 512
#define TILE 4096
#define CSR_CAP 10240
#define FINBLK 2048

typedef int   i4 __attribute__((ext_vector_type(4)));
typedef float f4 __attribute__((ext_vector_type(4)));
typedef float fv2 __attribute__((ext_vector_type(2)));

#if defined(__has_builtin)
#if __has_builtin(__builtin_amdgcn_cvt_pk_f32_fp8) && __has_builtin(__builtin_amdgcn_cvt_pk_fp8_f32)
#define HW_FP8 1
#endif
#endif

__device__ __forceinline__ float sw_dec_e4m3(unsigned b) {
    unsigned s = b & 0x80, e = (b >> 3) & 15, mm = b & 7;
    float v;
    if (e) v = __uint_as_float(((e + 120u) << 23) | (mm << 20));
    else   v = (float)mm * 0.001953125f;
    return s ? -v : v;
}
__device__ __forceinline__ unsigned sw_enc_e4m3(float f) {
    unsigned s = (__float_as_uint(f) & 0x80000000u) ? 0x80u : 0u;
    float a = fminf(fabsf(f), 448.0f);
    if (a < 9.765625e-4f) return s;
    if (a < 0.015625f) {
        int k = (int)rintf(a * 512.0f);
        if (k > 7) return s | 0x08;
        return s | (unsigned)k;
    }
    int e; float mant = frexpf(a, &e);
    int q = (int)rintf((mant * 2.0f - 1.0f) * 8.0f);
    int E = e - 1;
    if (q == 8) { q = 0; E += 1; }
    if (E > 8) { E = 8; q = 6; }
    return s | ((unsigned)(E + 7) << 3) | (unsigned)q;
}

__device__ __forceinline__ float2 f8pair(unsigned u) {   // 2 fp8 in low 16 bits
#ifdef HW_FP8
    fv2 r = __builtin_amdgcn_cvt_pk_f32_fp8((int)u, false);
    return make_float2(r.x, r.y);
#else
    return make_float2(sw_dec_e4m3(u & 0xff), sw_dec_e4m3((u >> 8) & 0xff));
#endif
}
__device__ __forceinline__ unsigned f8pack4(float v0, float v1, float v2, float v3) {
#ifdef HW_FP8
    unsigned pk = (unsigned)__builtin_amdgcn_cvt_pk_fp8_f32(v0, v1, 0, false);
    pk = (unsigned)__builtin_amdgcn_cvt_pk_fp8_f32(v2, v3, (int)pk, true);
    return pk;
#else
    return sw_enc_e4m3(v0) | (sw_enc_e4m3(v1) << 8) |
           (sw_enc_e4m3(v2) << 16) | (sw_enc_e4m3(v3) << 24);
#endif
}

__device__ __forceinline__ ushort f2bf(float v) {        // f32 -> bf16 (rne)
    unsigned u = __float_as_uint(v);
    return (ushort)((u + 0x7fffu + ((u >> 16) & 1u)) >> 16);
}
__device__ __forceinline__ float bf2f(ushort b) {
    return __uint_as_float(((unsigned)b) << 16);
}

// ---------- pass 1: per-WG bucket histogram (LDS), int4 x4 streaming ----------
__global__ __launch_bounds__(PTHR) void k_hist1(const int* __restrict__ col,
                                                int* __restrict__ histG,
                                                int E, int nbkt, int chunk) {
    __shared__ int h[MAXBKT];
    for (int i = threadIdx.x; i < nbkt; i += PTHR) h[i] = 0;
    __syncthreads();
    int s = blockIdx.x * chunk, e = min(E, s + chunk);
    if (s < e) {
        int s4 = s >> 2, e4 = e >> 2;
        const i4* c4 = (const i4*)col;
        int t = s4 + threadIdx.x;
        for (; t + 3 * PTHR < e4; t += 4 * PTHR) {
            i4 a = __builtin_nontemporal_load(c4 + t);
            i4 b = __builtin_nontemporal_load(c4 + t + PTHR);
            i4 c = __builtin_nontemporal_load(c4 + t + 2 * PTHR);
            i4 d = __builtin_nontemporal_load(c4 + t + 3 * PTHR);
            atomicAdd(&h[(unsigned)a.x >> BKT_SH], 1); atomicAdd(&h[(unsigned)a.y >> BKT_SH], 1);
            atomicAdd(&h[(unsigned)a.z >> BKT_SH], 1); atomicAdd(&h[(unsigned)a.w >> BKT_SH], 1);
            atomicAdd(&h[(unsigned)b.x >> BKT_SH], 1); atomicAdd(&h[(unsigned)b.y >> BKT_SH], 1);
            atomicAdd(&h[(unsigned)b.z >> BKT_SH], 1); atomicAdd(&h[(unsigned)b.w >> BKT_SH], 1);
            atomicAdd(&h[(unsigned)c.x >> BKT_SH], 1); atomicAdd(&h[(unsigned)c.y >> BKT_SH], 1);
            atomicAdd(&h[(unsigned)c.z >> BKT_SH], 1); atomicAdd(&h[(unsigned)c.w >> BKT_SH], 1);
            atomicAdd(&h[(unsigned)d.x >> BKT_SH], 1); atomicAdd(&h[(unsigned)d.y >> BKT_SH], 1);
            atomicAdd(&h[(unsigned)d.z >> BKT_SH], 1); atomicAdd(&h[(unsigned)d.w >> BKT_SH], 1);
        }
        for (; t < e4; t += PTHR) {
            i4 a = __builtin_nontemporal_load(c4 + t);
            atomicAdd(&h[(unsigned)a.x >> BKT_SH], 1); atomicAdd(&h[(unsigned)a.y >> BKT_SH], 1);
            atomicAdd(&h[(unsigned)a.z >> BKT_SH], 1); atomicAdd(&h[(unsigned)a.w >> BKT_SH], 1);
        }
        for (int i = (e4 << 2) + threadIdx.x; i < e; i += PTHR)
            atomicAdd(&h[(unsigned)col[i] >> BKT_SH], 1);
    }
    __syncthreads();
    for (int i = threadIdx.x; i < nbkt; i += PTHR)
        histG[(size_t)i * PWG + blockIdx.x] = h[i];
}

// ---------- pass 2a: per-bucket exclusive scan over WGs (in place) ----------
__global__ __launch_bounds__(PWG) void k_hscan_a(int* __restrict__ histG,
                                                 int* __restrict__ total, int nbkt) {
    __shared__ int s[PWG];
    int b = blockIdx.x, t = threadIdx.x;
    int v = histG[(size_t)b * PWG + t];
    s[t] = v;
    __syncthreads();
    for (int d = 1; d < PWG; d <<= 1) {
        int a = (t >= d) ? s[t - d] : 0;
        __syncthreads();
        s[t] += a;
        __syncthreads();
    }
    histG[(size_t)b * PWG + t] = s[t] - v;
    if (t == PWG - 1) total[b] = s[t];
}

// ---------- pass 2b: bucket starts ----------
__global__ __launch_bounds__(1024) void k_hscan_b(const int* __restrict__ total,
                                                  int* __restrict__ bstart, int nbkt) {
    __shared__ int s[1024];
    int t = threadIdx.x;
    int v = (t < nbkt) ? total[t] : 0;
    s[t] = v;
    __syncthreads();
    for (int d = 1; d < 1024; d <<= 1) {
        int a = (t >= d) ? s[t - d] : 0;
        __syncthreads();
        s[t] += a;
        __syncthreads();
    }
    if (t < nbkt) bstart[t] = s[t] - v;
    if (t == nbkt - 1) bstart[nbkt] = s[t];
}

// ---------- pass 3: tile multisplit -> part[] written as coalesced runs ----------
__global__ __launch_bounds__(PPTHR) void k_part(const int* __restrict__ row,
                                                const int* __restrict__ col,
                                                const int* __restrict__ histG,
                                                const int* __restrict__ bstart,
                                                unsigned int* __restrict__ part,
                                                int E, int nbkt, int chunk) {
    __shared__ int hist[MAXBKT], hbase[MAXBKT], curl[MAXBKT], gcur[MAXBKT];
    __shared__ int ssc[PPTHR];
    __shared__ unsigned grouped[TILE];
    __shared__ ushort bkt16[TILE];
    int tid = threadIdx.x, wg = blockIdx.x;
    for (int i = tid; i < nbkt; i += PPTHR)
        gcur[i] = bstart[i] + histG[(size_t)i * PWG + wg];
    int s = wg * chunk, e = min(E, s + chunk);
    for (int ts = s; ts < e; ts += TILE) {
        int te = min(e, ts + TILE), tc = te - ts;
        for (int i = tid; i < nbkt; i += PPTHR) hist[i] = 0;
        __syncthreads();
        for (int i = ts + tid; i < te; i += PPTHR)
            atomicAdd(&hist[(unsigned)col[i] >> BKT_SH], 1);
        __syncthreads();
        int v = (tid < nbkt) ? hist[tid] : 0;
        ssc[tid] = v;
        __syncthreads();
        for (int d = 1; d < PPTHR; d <<= 1) {
            int a = (tid >= d) ? ssc[tid - d] : 0;
            __syncthreads();
            ssc[tid] += a;
            __syncthreads();
        }
        if (tid < nbkt) { hbase[tid] = ssc[tid] - v; curl[tid] = ssc[tid] - v; }
        __syncthreads();
        for (int i = ts + tid; i < te; i += PPTHR) {
            int c = col[i], r = row[i];
            int b = (unsigned)c >> BKT_SH;
            int p = atomicAdd(&curl[b], 1);
            grouped[p] = ((unsigned)r << BKT_SH) | (unsigned)(c & (BKT_SZ - 1));
            bkt16[p] = (ushort)b;
        }
        __syncthreads();
        for (int q = tid; q < tc; q += PPTHR) {
            int b = bkt16[q];
            part[gcur[b] + (q - hbase[b])] = grouped[q];
        }
        __syncthreads();
        for (int i = tid; i < nbkt; i += PPTHR) gcur[i] += hist[i];
        __syncthreads();
    }
}

// ---------- per-bucket: degrees, offs, dinv; csr staged in LDS ----------
__global__ __launch_bounds__(PTHR) void k_csr(const unsigned int* __restrict__ part,
                                              const int* __restrict__ bstart,
                                              int* __restrict__ offs,
                                              float* __restrict__ dinv,
                                              int* __restrict__ csr,
                                              int N, int E, int nbkt) {
    __shared__ int dg[BKT_SZ], sc[BKT_SZ], cur[BKT_SZ];
    __shared__ int stage[CSR_CAP];
    int b = blockIdx.x, tid = threadIdx.x;   // PTHR == BKT_SZ
    dg[tid] = 0;
    __syncthreads();
    int s = bstart[b], e = bstart[b + 1], cnt = e - s;
    for (int i = s + tid; i < e; i += PTHR)
        atomicAdd(&dg[part[i] & (BKT_SZ - 1)], 1);
    __syncthreads();
    int v = dg[tid];
    sc[tid] = v;
    __syncthreads();
    for (int d = 1; d < BKT_SZ; d <<= 1) {
        int a = (tid >= d) ? sc[tid - d] : 0;
        __syncthreads();
        sc[tid] += a;
        __syncthreads();
    }
    int ex = sc[tid] - v;
    cur[tid] = ex;
    int g = b * BKT_SZ + tid;
    if (g < N) {
        offs[g] = s + ex;
        dinv[g] = rsqrtf((float)v + 1.0f);   // +1 self loop
    }
    if (b == 0 && tid == 0) offs[N] = E;
    __syncthreads();
    if (cnt <= CSR_CAP) {
        for (int i = s + tid; i < e; i += PTHR) {
            unsigned u = part[i];
            int p = atomicAdd(&cur[u & (BKT_SZ - 1)], 1);
            stage[p] = (int)(u >> BKT_SH);
        }
        __syncthreads();
        for (int q = tid; q < cnt; q += PTHR)
            csr[s + q] = stage[q];           // coalesced
    } else {                                  // safety fallback (scattered)
        for (int i = s + tid; i < e; i += PTHR) {
            unsigned u = part[i];
            int p = atomicAdd(&cur[u & (BKT_SZ - 1)], 1);
            csr[s + p] = (int)(u >> BKT_SH);
        }
    }
}

// ---------- xws = dinv * (x @ W1), fp8 e4m3 (64B rows) ----------
__global__ __launch_bounds__(256) void k_gemm1(const float* __restrict__ x,
                                               const float* __restrict__ W1,
                                               const float* __restrict__ dinv,
                                               unsigned int* __restrict__ xw8,
                                               int N) {
    __shared__ float xs[64 * 132];
    __shared__ float ws[128 * 64];
    int tid = threadIdx.x;
    int row0 = blockIdx.x * 64;

    const float4* w4 = (const float4*)W1;
    float4* ws4 = (float4*)ws;
#pragma unroll
    for (int i = 0; i < 8; i++) ws4[tid + 256 * i] = w4[tid + 256 * i];

#pragma unroll
    for (int i = 0; i < 8; i++) {
        int idx = tid + 256 * i;
        int r = idx >> 5;
        int c = idx & 31;
        f4 v = {0.f, 0.f, 0.f, 0.f};
        int gr = row0 + r;
        if (gr < N) v = __builtin_nontemporal_load((const f4*)x + (size_t)gr * 32 + c);
        *(f4*)&xs[r * 132 + c * 4] = v;
    }
    __syncthreads();

    int tx = tid & 15, ty = tid >> 4;
    float acc[4][4] = {};
#pragma unroll 4
    for (int k = 0; k < 128; k++) {
        float4 wv = *(const float4*)&ws[k * 64 + tx * 4];
#pragma unroll
        for (int i = 0; i < 4; i++) {
            float xv = xs[(ty * 4 + i) * 132 + k];
            acc[i][0] += xv * wv.x;
            acc[i][1] += xv * wv.y;
            acc[i][2] += xv * wv.z;
            acc[i][3] += xv * wv.w;
        }
    }
#pragma unroll
    for (int i = 0; i < 4; i++) {
        int gr = row0 + ty * 4 + i;
        if (gr < N) {
            float dsc = dinv[gr];
            unsigned pk = f8pack4(acc[i][0] * dsc, acc[i][1] * dsc,
                                  acc[i][2] * dsc, acc[i][3] * dsc);
            xw8[(size_t)gr * 16 + tx] = pk;   // row = 16 u32 = 64 fp8
        }
    }
}

// ---------- aggregation: one wave per node, half-wave ushort fp8 gathers ----------
__global__ __launch_bounds__(256) void k_agg(const ushort* __restrict__ xw8,
                                             const int* __restrict__ csr,
                                             const int* __restrict__ offs,
                                             const float* __restrict__ dinv,
                                             const float* __restrict__ b1,
                                             const float* __restrict__ W2,
                                             float* __restrict__ yp,
                                             ushort* __restrict__ yph, int N) {
    int wid = (blockIdx.x * blockDim.x + threadIdx.x) >> 6;
    int lane = threadIdx.x & 63;
    if (wid >= N) return;
    int m = lane & 31, half = lane >> 5;

    float di = dinv[wid];
    float2 bv = ((const float2*)b1)[m];
    float2 wv = ((const float2*)W2)[m];

    float a0 = 0.f, a1 = 0.f;
    if (half == 0) {          // self loop counted once
        float2 sv = f8pair(xw8[(size_t)wid * 32 + m]);
        a0 += sv.x; a1 += sv.y;
    }
    int p = offs[wid], pe = offs[wid + 1];
    for (; p + 16 <= pe; p += 16) {
        int j0 = csr[p + 0 + half];
        int j1 = csr[p + 2 + half];
        int j2 = csr[p + 4 + half];
        int j3 = csr[p + 6 + half];
        int j4 = csr[p + 8 + half];
        int j5 = csr[p + 10 + half];
        int j6 = csr[p + 12 + half];
        int j7 = csr[p + 14 + half];
        ushort u0 = xw8[(size_t)j0 * 32 + m];
        ushort u1 = xw8[(size_t)j1 * 32 + m];
        ushort u2 = xw8[(size_t)j2 * 32 + m];
        ushort u3 = xw8[(size_t)j3 * 32 + m];
        ushort u4 = xw8[(size_t)j4 * 32 + m];
        ushort u5 = xw8[(size_t)j5 * 32 + m];
        ushort u6 = xw8[(size_t)j6 * 32 + m];
        ushort u7 = xw8[(size_t)j7 * 32 + m];
        float2 v0 = f8pair(u0), v1 = f8pair(u1), v2 = f8pair(u2), v3 = f8pair(u3);
        float2 v4 = f8pair(u4), v5 = f8pair(u5), v6 = f8pair(u6), v7 = f8pair(u7);
        a0 += ((v0.x + v1.x) + (v2.x + v3.x)) + ((v4.x + v5.x) + (v6.x + v7.x));
        a1 += ((v0.y + v1.y) + (v2.y + v3.y)) + ((v4.y + v5.y) + (v6.y + v7.y));
    }
    for (; p + 8 <= pe; p += 8) {
        int j0 = csr[p + 0 + half];
        int j1 = csr[p + 2 + half];
        int j2 = csr[p + 4 + half];
        int j3 = csr[p + 6 + half];
        float2 v0 = f8pair(xw8[(size_t)j0 * 32 + m]);
        float2 v1 = f8pair(xw8[(size_t)j1 * 32 + m]);
        float2 v2 = f8pair(xw8[(size_t)j2 * 32 + m]);
        float2 v3 = f8pair(xw8[(size_t)j3 * 32 + m]);
        a0 += (v0.x + v1.x) + (v2.x + v3.x);
        a1 += (v0.y + v1.y) + (v2.y + v3.y);
    }
    for (; p + 2 <= pe; p += 2) {
        int j = csr[p + half];
        float2 v = f8pair(xw8[(size_t)j * 32 + m]);
        a0 += v.x; a1 += v.y;
    }
    if (p < pe && half == 0) {     // odd tail edge
        int j = csr[p];
        float2 v = f8pair(xw8[(size_t)j * 32 + m]);
        a0 += v.x; a1 += v.y;
    }
    a0 += __shfl_xor(a0, 32, 64);
    a1 += __shfl_xor(a1, 32, 64);
    float h0 = fmaxf(bv.x + di * a0, 0.f);
    float h1 = fmaxf(bv.y + di * a1, 0.f);
    float v = h0 * wv.x + h1 * wv.y;
#pragma unroll
    for (int d = 16; d > 0; d >>= 1) v += __shfl_xor(v, d, 64);
    if (lane == 0) {
        float ypv = di * v;
        yp[wid] = ypv;
        yph[wid] = f2bf(ypv);    // 200KB bf16 copy for final2's hot gathers
    }
}

// ---------- final: wave-per-node over CSR (bf16 yph gathers), per-block partials ----------
__global__ __launch_bounds__(256) void k_final2(const int* __restrict__ csr,
                                                const int* __restrict__ offs,
                                                const float* __restrict__ dinv,
                                                const float* __restrict__ yp,
                                                const ushort* __restrict__ yph,
                                                float* __restrict__ partial, int N) {
    int lane = threadIdx.x & 63, w = threadIdx.x >> 6;
    int nwave_tot = gridDim.x * 4;
    int wid0 = blockIdx.x * 4 + w;
    float wpart = 0.f;
    for (int i = wid0; i < N; i += nwave_tot) {
        int p0 = offs[i], p1 = offs[i + 1];
        float s = (lane == 0) ? yp[i] : 0.f;
        for (int p = p0 + lane; p < p1; p += 64)
            s += bf2f(yph[csr[p]]);
#pragma unroll
        for (int d = 32; d > 0; d >>= 1) s += __shfl_xor(s, d, 64);
        if (lane == 0) wpart += dinv[i] * s;
    }
    __shared__ float wsum[4];
    if (lane == 0) wsum[w] = wpart;
    __syncthreads();
    if (threadIdx.x == 0)
        partial[blockIdx.x] = (wsum[0] + wsum[1]) + (wsum[2] + wsum[3]);
}

// ---------- reduce partials + write ----------
__global__ __launch_bounds__(256) void k_write(const float* __restrict__ partial,
                                               const float* __restrict__ b2,
                                               float* __restrict__ out, int nb, int N) {
    float s = 0.f;
    for (int i = threadIdx.x; i < nb; i += 256) s += partial[i];
#pragma unroll
    for (int d = 32; d > 0; d >>= 1) s += __shfl_xor(s, d, 64);
    __shared__ float wsum[4];
    int lane = threadIdx.x & 63, w = threadIdx.x >> 6;
    if (lane == 0) wsum[w] = s;
    __syncthreads();
    if (threadIdx.x == 0)
        out[0] = b2[0] + ((wsum[0] + wsum[1]) + (wsum[2] + wsum[3])) / (float)N;
}

extern "C" void kernel_launch(void* const* d_in, const int* in_sizes, int n_in,
                              void* d_out, int out_size, void* d_ws, size_t ws_size,
                              hipStream_t stream) {
    const float* x  = (const float*)d_in[0];
    const int*   ei = (const int*)d_in[1];
    const float* W1 = (const float*)d_in[2];
    const float* b1 = (const float*)d_in[3];
    const float* W2 = (const float*)d_in[4];
    const float* b2 = (const float*)d_in[5];

    int N = in_sizes[0] / F_IN;
    int E = in_sizes[1] / 2;
    const int* erow = ei;        // sources
    const int* ecol = ei + E;    // targets

    int NBKT = (N + BKT_SZ - 1) >> BKT_SH;          // 391
    int chunk = (((E + PWG - 1) / PWG) + 3) & ~3;   // 4-aligned chunks

    char* w = (char*)d_ws;
    auto take = [&](size_t bytes) {
        char* p = w;
        w += (bytes + 255) & ~(size_t)255;
        return p;
    };
    int*          histG   = (int*)take((size_t)NBKT * PWG * 4);
    int*          total   = (int*)take((size_t)NBKT * 4);
    int*          bstart  = (int*)take((size_t)(NBKT + 1) * 4);
    unsigned int* part    = (unsigned int*)take((size_t)E * 4);
    int*          csr     = (int*)take((size_t)E * 4);
    int*          offs    = (int*)take((size_t)(N + 1) * 4);
    float*        dinv    = (float*)take((size_t)N * 4);
    float*        yp      = (float*)take((size_t)N * 4);
    ushort*       yph     = (ushort*)take((size_t)N * 2);
    float*        partial = (float*)take((size_t)FINBLK * 4);
    unsigned int* xw8     = (unsigned int*)take((size_t)N * H_DIM);
    (void)ws_size;

    float* out = (float*)d_out;

    k_hist1<<<PWG, PTHR, 0, stream>>>(ecol, histG, E, NBKT, chunk);
    k_hscan_a<<<NBKT, PWG, 0, stream>>>(histG, total, NBKT);
    k_hscan_b<<<1, 1024, 0, stream>>>(total, bstart, NBKT);
    k_part<<<PWG, PPTHR, 0, stream>>>(erow, ecol, histG, bstart, part, E, NBKT, chunk);
    k_csr<<<NBKT, PTHR, 0, stream>>>(part, bstart, offs, dinv, csr, N, E, NBKT);
    k_gemm1<<<(N + 63) / 64, 256, 0, stream>>>(x, W1, dinv, xw8, N);
    k_agg<<<((size_t)N * 64 + 255) / 256, 256, 0, stream>>>((const ushort*)xw8, csr, offs, dinv, b1, W2, yp, yph, N);
    k_final2<<<FINBLK, 256, 0, stream>>>(csr, offs, dinv, yp, yph, partial, N);
    k_write<<<1, 256, 0, stream>>>(partial, b2, out, FINBLK, N);
}